// Round 19
// baseline (125.664 us; speedup 1.0000x reference)
//
#include <hip/hip_runtime.h>
#include <math.h>

// Problem constants
#define Bq 2
#define Nn 20000
#define Ee 20000
#define Aa 8
#define Hh 256
#define TEe 32
#define NTy 16
constexpr int BE   = Bq * Ee;    // 40000
constexpr int BN   = Bq * Nn;    // 40000
constexpr int KTE  = 8;          // We1 K-tiles (256/32)
constexpr int KTU  = 16;         // Wupd K-tiles: W1 = kt 0-7, W2 = kt 8-15
constexpr int LDA  = 264;        // padded A row (ushorts) = 33 uint4
constexpr int CAP  = 64;         // incidence bucket capacity
// k_prep partition
constexpr int PB_DET  = 256;
constexpr int PB_PKE  = 32;
constexpr int PB_PKU  = 64;
constexpr int PB_TB   = 1;
constexpr int PB_ZD   = 64;
constexpr int NPREP   = PB_DET + PB_PKE + PB_PKU + PB_TB + PB_ZD + 1;
// launch B: fill (bid%3==2) | E-GEMM; 1890 = 630 fill + 1260 slots (1250 used)
constexpr int NFB     = 1890;
constexpr int NFILL3  = NFB / 3;             // 630
// launch C: U-GEMM (even) | edge_w2 (odd)
constexpr int NUC     = 2500;

typedef __attribute__((ext_vector_type(8))) short bf16x8;
typedef __attribute__((ext_vector_type(8))) unsigned short u16x8;
typedef __attribute__((ext_vector_type(4))) float f32x4;
typedef unsigned short u16;
typedef unsigned int   u32;

__device__ __forceinline__ u16 f2bf(float f) {           // RNE f32 -> bf16
    u32 u = __float_as_uint(f);
    u32 r = u + 0x7FFFu + ((u >> 16) & 1u);
    return (u16)(r >> 16);
}
__device__ __forceinline__ float bf2f(u16 h) {
    return __uint_as_float(((u32)h) << 16);
}
__device__ __forceinline__ float gelu_f(float x) {
    return 0.5f * x * (1.f + erff(x * 0.70710678118654752440f));
}
__device__ __forceinline__ f32x4 mfma16(bf16x8 a, bf16x8 b, f32x4 c) {
    return __builtin_amdgcn_mfma_f32_16x16x32_bf16(a, b, c, 0, 0, 0);
}

// mask dtype sniffing: bit1 => f32 mask, bit0 => u8 mask, none => i32
__device__ __forceinline__ float mask_at(const void* mp, int flag, int i) {
    if (flag & 2) return ((const float*)mp)[i];
    if (flag & 1) return ((const unsigned char*)mp)[i] ? 1.f : 0.f;
    return ((const int*)mp)[i] ? 1.f : 0.f;
}

// shared BM=32 dense GEMM body: stage nf -> LDS, 8 kt, store bf16 out
__device__ __forceinline__ void gemm32_body(
    u16 (*s_a)[LDA], int tid, int n0, const float* __restrict__ nf,
    const bf16x8* __restrict__ Wp, int kstride, int ktoff,
    uint4* __restrict__ outb) {
    const int w = tid >> 6, lane = tid & 63;
    const int l15 = lane & 15, lg = lane >> 4;

    {   // stage nf f32 -> bf16 LDS
        const float4* nf4 = (const float4*)nf + (size_t)n0 * 64;
        #pragma unroll
        for (int i = 0; i < 8; i++) {
            int idx = i * 256 + tid;
            int r = idx >> 6, cc = idx & 63;
            float4 v = nf4[r * 64 + cc];
            ushort4 u; u.x = f2bf(v.x); u.y = f2bf(v.y);
            u.z = f2bf(v.z); u.w = f2bf(v.w);
            *(ushort4*)&s_a[r][cc * 4] = u;
        }
    }
    __syncthreads();

    f32x4 acc[2][4];
    #pragma unroll
    for (int m = 0; m < 2; m++)
        #pragma unroll
        for (int n = 0; n < 4; n++) acc[m][n] = (f32x4){0.f, 0.f, 0.f, 0.f};

    #pragma unroll
    for (int kt = 0; kt < 8; kt++) {
        bf16x8 afr[2], bfr[4];
        #pragma unroll
        for (int n = 0; n < 4; n++)
            bfr[n] = Wp[((size_t)((w * 4 + n) * kstride + ktoff + kt)) * 64 + lane];
        #pragma unroll
        for (int m = 0; m < 2; m++)
            afr[m] = *(const bf16x8*)&s_a[m * 16 + l15][kt * 32 + lg * 8];
        #pragma unroll
        for (int m = 0; m < 2; m++)
            #pragma unroll
            for (int n = 0; n < 4; n++)
                acc[m][n] = mfma16(afr[m], bfr[n], acc[m][n]);
    }
    __syncthreads();
    #pragma unroll
    for (int m = 0; m < 2; m++)
        #pragma unroll
        for (int j = 0; j < 4; j++) {
            int r = m * 16 + lg * 4 + j;
            #pragma unroll
            for (int n = 0; n < 4; n++)
                s_a[r][w * 64 + n * 16 + l15] = f2bf(acc[m][n][j]);
        }
    __syncthreads();
    const uint4* sa4 = (const uint4*)&s_a[0][0];
    #pragma unroll
    for (int i = 0; i < 4; i++) {
        int idx = i * 256 + tid;
        int r = idx >> 5, cc = idx & 31;
        outb[(size_t)(n0 + r) * 32 + cc] = sa4[r * 33 + cc];
    }
}

// prep: detect | pack(Wenc[0:256]) | pack(Wupd) | type_bias | zero-deg | dummy
__global__ __launch_bounds__(256) void k_prep(
    const unsigned int* __restrict__ mw, int nmw, int* __restrict__ flag,
    const float* __restrict__ Wenc, u16* __restrict__ WeP,
    const float* __restrict__ Wupd, u16* __restrict__ WuP,
    const float* __restrict__ ett, const float* __restrict__ benc,
    float* __restrict__ tb, int* __restrict__ deg,
    float4* __restrict__ dummy) {
    __shared__ float s_e[NTy * TEe];
    const int bid = blockIdx.x;
    const int tid = threadIdx.x;

    if (bid < PB_DET) {                        // ---- mask dtype detect
        int found = 0;
        for (int i = bid * 256 + tid; i < nmw; i += PB_DET * 256) {
            unsigned int w = mw[i];
            if (w == 0x3F800000u) found |= 2;
            else if (w > 1u) found |= 1;
        }
        __shared__ int sf;
        if (tid == 0) sf = 0;
        __syncthreads();
        if (found) atomicOr(&sf, found);
        __syncthreads();
        if (tid == 0 && sf) atomicOr(flag, sf);
    } else if (bid < PB_DET + PB_PKE) {        // ---- pack Wenc rows 0..255
        int t = (bid - PB_DET) * 256 + tid;
        int lane = t & 63, tile = t >> 6;
        int kt = tile % KTE, nt = tile / KTE;
        int kbase = kt * 32 + (lane >> 4) * 8;
        int col = nt * 16 + (lane & 15);
        u16 tmp[8];
        #pragma unroll
        for (int j = 0; j < 8; j++)
            tmp[j] = f2bf(Wenc[(size_t)(kbase + j) * Hh + col]);
        *(uint4*)(WeP + (size_t)t * 8) = *(const uint4*)tmp;
    } else if (bid < PB_DET + PB_PKE + PB_PKU) {   // ---- pack Wupd
        int t = (bid - PB_DET - PB_PKE) * 256 + tid;
        int lane = t & 63, tile = t >> 6;
        int kt = tile % KTU, nt = tile / KTU;
        int kbase = kt * 32 + (lane >> 4) * 8;
        int col = nt * 16 + (lane & 15);
        u16 tmp[8];
        #pragma unroll
        for (int j = 0; j < 8; j++)
            tmp[j] = f2bf(Wupd[(size_t)(kbase + j) * Hh + col]);
        *(uint4*)(WuP + (size_t)t * 8) = *(const uint4*)tmp;
    } else if (bid < PB_DET + PB_PKE + PB_PKU + PB_TB) {   // ---- type_bias
        for (int i = tid; i < NTy * TEe; i += 256) s_e[i] = ett[i];
        __syncthreads();
        float b = benc[tid];
        for (int t = 0; t < NTy; t++) {
            float acc = b;
            #pragma unroll 8
            for (int k = 0; k < TEe; k++)
                acc = fmaf(s_e[t * TEe + k], Wenc[(size_t)(Hh + k) * Hh + tid], acc);
            tb[t * Hh + tid] = acc;
        }
    } else if (bid < PB_DET + PB_PKE + PB_PKU + PB_TB + PB_ZD) {  // ---- zero deg
        for (int i = (bid - PB_DET - PB_PKE - PB_PKU - PB_TB) * 256 + tid;
             i < BN; i += PB_ZD * 256)
            deg[i] = 0;
    } else {                                   // ---- zero efW2 dummy row
        if (tid < Hh * 2 / 16) {
            float4 z; z.x = 0.f; z.y = 0.f; z.z = 0.f; z.w = 0.f;
            dummy[tid] = z;
        }
    }
}

// launch B: bucket fill | E-GEMM (nfWe1 = nf@We1), interleaved %3
__global__ __launch_bounds__(256) void k_fill_egemm(
    const int* __restrict__ members, const void* __restrict__ maskp,
    const int* __restrict__ flagp, int* __restrict__ deg,
    int* __restrict__ list2,
    const float* __restrict__ nf, const bf16x8* __restrict__ WeP,
    uint4* __restrict__ nfWe1) {
    __shared__ __align__(16) u16 s_a[32][LDA];
    const int bid = blockIdx.x;
    const int tid = threadIdx.x;

    if (bid % 3 == 2) {                       // ---- bucket fill (630 blocks)
        const int fbid = bid / 3;
        int flag = flagp[0];
        for (int i = fbid * 256 + tid; i < BE * Aa; i += NFILL3 * 256) {
            if (mask_at(maskp, flag, i) != 0.f) {
                int ge = i >> 3;
                int b = ge / Ee;
                int idx = min(max(members[i], 0), Nn - 1);
                int node = b * Nn + idx;
                int slot = atomicAdd(&deg[node], 1);
                if (slot < CAP) list2[(size_t)node * CAP + slot] = ge;
            }
        }
        return;
    }
    const int gbid = (bid / 3) * 2 + (bid % 3);
    if (gbid >= BN / 32) return;
    gemm32_body(s_a, tid, gbid * 32, nf, WeP, KTE, 0, nfWe1);
}

// launch C: U-GEMM (even bids: nfW1 = nf@Wupd[0:256]) | edge_w2 (odd bids)
__global__ __launch_bounds__(256) void k_ugemm_edge(
    const float* __restrict__ nf, const bf16x8* __restrict__ WuP,
    uint4* __restrict__ nfW1,
    const int* __restrict__ members, const void* __restrict__ maskp,
    const int* __restrict__ flagp, const int* __restrict__ types,
    const u16* __restrict__ nfWe1, const float* __restrict__ tb,
    const float* __restrict__ genc, const float* __restrict__ beenc,
    uint4* __restrict__ efW2) {
    __shared__ __align__(16) u16 s_a[32][LDA];
    const int bid = blockIdx.x;
    const int tid = threadIdx.x;

    if ((bid & 1) == 0) {                     // ---- U-GEMM
        gemm32_body(s_a, tid, (bid >> 1) * 32, nf, WuP, KTU, 0, nfW1);
        return;
    }
    // ---- edge phase + W2 GEMM
    const int e0  = (bid >> 1) * 32;
    const int w = tid >> 6, lane = tid & 63;
    const int l15 = lane & 15, lg = lane >> 4;
    const int flag = flagp[0];
    const int colb = (lane & 31) * 8;
    const int half = lane >> 5;
    const int colw = colb + half * 4;

    {
        const int ew0 = e0 + w * 8;
        int base = ew0 * Aa + lane;
        int mem_all = members[base];
        float mv_all = mask_at(maskp, flag, base);
        int er = ew0 + (lane >> 3);
        int idxv = min(max(mem_all, 0), Nn - 1) + ((er >= Ee) ? Nn : 0);

        float4 gm = *(const float4*)(genc + colw);
        float4 bt = *(const float4*)(beenc + colw);

        for (int i = 0; i < 8; i++) {
            int e = ew0 + i;
            float c = 0.f;
            #pragma unroll
            for (int a = 0; a < Aa; a++) c += __shfl(mv_all, i * 8 + a, 64);
            u16x8 v[4]; float mw_[4];
            #pragma unroll
            for (int q = 0; q < 4; q++) {
                int a = 2 * q + half;
                int gi = __shfl(idxv, i * 8 + a, 64);
                mw_[q] = __shfl(mv_all, i * 8 + a, 64);
                v[q] = *(const u16x8*)(nfWe1 + (size_t)gi * Hh + colb);
            }
            float acc[8];
            #pragma unroll
            for (int k = 0; k < 8; k++) acc[k] = 0.f;
            #pragma unroll
            for (int q = 0; q < 4; q++)
                #pragma unroll
                for (int k = 0; k < 8; k++)
                    acc[k] = fmaf(mw_[q], bf2f(v[q][k]), acc[k]);
            #pragma unroll
            for (int k = 0; k < 8; k++) acc[k] += __shfl_xor(acc[k], 32, 64);
            const float rc = 1.f / fmaxf(c, 1.f);
            float x0 = half ? acc[4] : acc[0];
            float x1 = half ? acc[5] : acc[1];
            float x2 = half ? acc[6] : acc[2];
            float x3 = half ? acc[7] : acc[3];
            int t = types[e];
            float4 tbv = *(const float4*)(tb + t * Hh + colw);
            float g0 = gelu_f(fmaf(x0, rc, tbv.x));
            float g1 = gelu_f(fmaf(x1, rc, tbv.y));
            float g2 = gelu_f(fmaf(x2, rc, tbv.z));
            float g3 = gelu_f(fmaf(x3, rc, tbv.w));
            float s  = g0 + g1 + g2 + g3;
            float s2 = fmaf(g0, g0, fmaf(g1, g1, fmaf(g2, g2, g3 * g3)));
            #pragma unroll
            for (int mk = 1; mk < 64; mk <<= 1) {
                s  += __shfl_xor(s, mk, 64);
                s2 += __shfl_xor(s2, mk, 64);
            }
            float mu = s * (1.f / Hh);
            float rs = rsqrtf(s2 * (1.f / Hh) - mu * mu + 1e-5f);
            ushort4 o;
            o.x = f2bf((g0 - mu) * rs * gm.x + bt.x);
            o.y = f2bf((g1 - mu) * rs * gm.y + bt.y);
            o.z = f2bf((g2 - mu) * rs * gm.z + bt.z);
            o.w = f2bf((g3 - mu) * rs * gm.w + bt.w);
            *(ushort4*)&s_a[w * 8 + i][colw] = o;
        }
    }
    __syncthreads();

    f32x4 acc[2][4];
    #pragma unroll
    for (int m = 0; m < 2; m++)
        #pragma unroll
        for (int n = 0; n < 4; n++) acc[m][n] = (f32x4){0.f, 0.f, 0.f, 0.f};

    #pragma unroll
    for (int kt = 0; kt < 8; kt++) {     // Wupd kt 8..15 = W2
        bf16x8 bfr[4], afr[2];
        #pragma unroll
        for (int n = 0; n < 4; n++)
            bfr[n] = WuP[((size_t)((w * 4 + n) * KTU + 8 + kt)) * 64 + lane];
        #pragma unroll
        for (int m = 0; m < 2; m++)
            afr[m] = *(const bf16x8*)&s_a[m * 16 + l15][kt * 32 + lg * 8];
        #pragma unroll
        for (int m = 0; m < 2; m++)
            #pragma unroll
            for (int n = 0; n < 4; n++)
                acc[m][n] = mfma16(afr[m], bfr[n], acc[m][n]);
    }
    __syncthreads();
    #pragma unroll
    for (int m = 0; m < 2; m++)
        #pragma unroll
        for (int j = 0; j < 4; j++) {
            int r = m * 16 + lg * 4 + j;
            #pragma unroll
            for (int n = 0; n < 4; n++)
                s_a[r][w * 64 + n * 16 + l15] = f2bf(acc[m][n][j]);
        }
    __syncthreads();
    const uint4* sa4 = (const uint4*)&s_a[0][0];
    #pragma unroll
    for (int i = 0; i < 4; i++) {
        int idx = i * 256 + tid;
        int r = idx >> 5, cc = idx & 31;
        efW2[(size_t)(e0 + r) * 32 + cc] = sa4[r * 33 + cc];
    }
}

// node finish: half-wave bucket gather-avg efW2 + nfW1 + bias -> gelu -> LN
__global__ __launch_bounds__(512) void k_node_final(
    const u16* __restrict__ efW2, const u16* __restrict__ nfW1,
    const int* __restrict__ deg, const int* __restrict__ list2,
    const float* __restrict__ bupd, const float* __restrict__ gupd,
    const float* __restrict__ beupd, float* __restrict__ out) {
    const int n = (blockIdx.x * 512 + threadIdx.x) >> 6;
    const int lane = threadIdx.x & 63;
    if (n >= BN) return;
    const int d = min(deg[n], CAP);
    const size_t base = (size_t)n * CAP;
    const int colb = (lane & 31) * 8;
    const int half = lane >> 5;
    const int colw = colb + half * 4;

    int lv = (lane < d) ? list2[base + lane] : BE;

    float acc[8];
    #pragma unroll
    for (int k = 0; k < 8; k++) acc[k] = 0.f;

    for (int j0 = 0; j0 < d; j0 += 8) {
        u16x8 v[4];
        #pragma unroll
        for (int q = 0; q < 4; q++) {
            int jj = j0 + 2 * q + half;
            int ge = __shfl(lv, jj & 63, 64);
            if (jj >= d) ge = BE;
            v[q] = *(const u16x8*)(efW2 + (size_t)ge * Hh + colb);
        }
        #pragma unroll
        for (int q = 0; q < 4; q++)
            #pragma unroll
            for (int k = 0; k < 8; k++)
                acc[k] += bf2f(v[q][k]);
    }
    #pragma unroll
    for (int k = 0; k < 8; k++) acc[k] += __shfl_xor(acc[k], 32, 64);

    const float rc = 1.f / fmaxf((float)d, 1.f);
    float x0 = half ? acc[4] : acc[0];
    float x1 = half ? acc[5] : acc[1];
    float x2 = half ? acc[6] : acc[2];
    float x3 = half ? acc[7] : acc[3];
    ushort4 w1 = *(const ushort4*)(nfW1 + (size_t)n * Hh + colw);
    float4 bb = *(const float4*)(bupd + colw);
    float g0 = gelu_f(fmaf(x0, rc, bf2f(w1.x) + bb.x));
    float g1 = gelu_f(fmaf(x1, rc, bf2f(w1.y) + bb.y));
    float g2 = gelu_f(fmaf(x2, rc, bf2f(w1.z) + bb.z));
    float g3 = gelu_f(fmaf(x3, rc, bf2f(w1.w) + bb.w));

    float s  = g0 + g1 + g2 + g3;
    float s2 = fmaf(g0, g0, fmaf(g1, g1, fmaf(g2, g2, g3 * g3)));
    #pragma unroll
    for (int mk = 1; mk < 64; mk <<= 1) {
        s  += __shfl_xor(s, mk, 64);
        s2 += __shfl_xor(s2, mk, 64);
    }
    float mu = s * (1.f / Hh);
    float rs = rsqrtf(s2 * (1.f / Hh) - mu * mu + 1e-5f);

    float4 gm = *(const float4*)(gupd + colw);
    float4 bt = *(const float4*)(beupd + colw);
    float4 o;
    o.x = (g0 - mu) * rs * gm.x + bt.x;
    o.y = (g1 - mu) * rs * gm.y + bt.y;
    o.z = (g2 - mu) * rs * gm.z + bt.z;
    o.w = (g3 - mu) * rs * gm.w + bt.w;
    *(float4*)(out + (size_t)n * Hh + colw) = o;
}

extern "C" void kernel_launch(void* const* d_in, const int* in_sizes, int n_in,
                              void* d_out, int out_size, void* d_ws, size_t ws_size,
                              hipStream_t stream) {
    const float* nf    = (const float*)d_in[0];
    const int* members = (const int*)d_in[1];
    const int* types   = (const int*)d_in[2];
    const void* maskp  = d_in[3];
    const float* ett   = (const float*)d_in[4];
    const float* Wenc  = (const float*)d_in[5];
    const float* benc  = (const float*)d_in[6];
    const float* genc  = (const float*)d_in[7];
    const float* beenc = (const float*)d_in[8];
    const float* Wupd  = (const float*)d_in[9];
    const float* bupd  = (const float*)d_in[10];
    const float* gupd  = (const float*)d_in[11];
    const float* beupd = (const float*)d_in[12];
    float* out = (float*)d_out;

    // workspace layout (~72 MB; ws is 256 MiB)
    int* ip    = (int*)d_ws;
    int* flag  = ip;                      // 64 ints
    int* deg   = ip + 64;                 // BN
    int* list2 = deg + BN;                // BN*CAP (10.24 MB)
    char* p    = (char*)(list2 + (size_t)BN * CAP);
    u16* efW2b  = (u16*)p;   p += (size_t)(BE + 1) * Hh * 2;       // 20.5 MB (+zero row)
    u16* nfW1b  = (u16*)p;   p += (size_t)BN * Hh * 2;             // 20.5 MB
    u16* nfWe1b = (u16*)p;   p += (size_t)BN * Hh * 2;             // 20.5 MB
    u16* We1P   = (u16*)p;   p += (size_t)16 * KTE * 64 * 8 * 2;   // 131 KB
    u16* WupdP  = (u16*)p;   p += (size_t)16 * KTU * 64 * 8 * 2;   // 262 KB
    float* tb   = (float*)p;                                       // 16 KB

    hipMemsetAsync(flag, 0, 256, stream);
    hipLaunchKernelGGL(k_prep, dim3(NPREP), dim3(256), 0, stream,
                       (const unsigned int*)maskp, BE * Aa / 4, flag,
                       Wenc, We1P, Wupd, WupdP, ett, benc, tb, deg,
                       (float4*)(efW2b + (size_t)BE * Hh));
    hipLaunchKernelGGL(k_fill_egemm, dim3(NFB), dim3(256), 0, stream,
                       members, maskp, flag, deg, list2,
                       nf, (const bf16x8*)We1P, (uint4*)nfWe1b);
    hipLaunchKernelGGL(k_ugemm_edge, dim3(NUC), dim3(256), 0, stream,
                       nf, (const bf16x8*)WupdP, (uint4*)nfW1b,
                       members, maskp, flag, types, nfWe1b, tb, genc, beenc,
                       (uint4*)efW2b);
    hipLaunchKernelGGL(k_node_final, dim3(BN * 64 / 512), dim3(512), 0, stream,
                       efW2b, nfW1b, deg, list2, bupd, gupd, beupd, out);
}

// Round 20
// 115.044 us; speedup vs baseline: 1.0923x; 1.0923x over previous
//
#include <hip/hip_runtime.h>
#include <math.h>

// Problem constants
#define Bq 2
#define Nn 20000
#define Ee 20000
#define Aa 8
#define Hh 256
#define TEe 32
#define NTy 16
constexpr int BE   = Bq * Ee;    // 40000
constexpr int BN   = Bq * Nn;    // 40000
constexpr int KTE  = 8;          // We1 K-tiles (256/32)
constexpr int KTU  = 16;         // Wupd K-tiles: W1 = kt 0-7, W2 = kt 8-15
constexpr int LDA  = 264;        // padded A row (ushorts) = 33 uint4
constexpr int CAP  = 64;         // incidence bucket capacity
// k_prep partition: detect | packWe | packWu | type_bias | zero-deg | zero-dummy
constexpr int PB_DET  = 256;
constexpr int PB_PKE  = 32;
constexpr int PB_PKU  = 64;
constexpr int PB_TB   = 1;
constexpr int PB_ZD   = 64;
constexpr int NPREP   = PB_DET + PB_PKE + PB_PKU + PB_TB + PB_ZD + 1;
// k_fill_dual (512-thread blocks): fill = (bid%3==2), gemm = rest
// GEMM needs BN/32 = 1250 blocks. 1875 = 625 fill + 1250 gemm.
constexpr int NFD     = 1875;
constexpr int NFILL3  = NFD / 3;             // 625 (x512 thr = exactly BE*Aa)

typedef __attribute__((ext_vector_type(8))) short bf16x8;
typedef __attribute__((ext_vector_type(8))) unsigned short u16x8;
typedef __attribute__((ext_vector_type(4))) float f32x4;
typedef unsigned short u16;
typedef unsigned int   u32;

__device__ __forceinline__ u16 f2bf(float f) {           // RNE f32 -> bf16
    u32 u = __float_as_uint(f);
    u32 r = u + 0x7FFFu + ((u >> 16) & 1u);
    return (u16)(r >> 16);
}
__device__ __forceinline__ float bf2f(u16 h) {
    return __uint_as_float(((u32)h) << 16);
}
__device__ __forceinline__ float gelu_f(float x) {
    return 0.5f * x * (1.f + erff(x * 0.70710678118654752440f));
}
__device__ __forceinline__ f32x4 mfma16(bf16x8 a, bf16x8 b, f32x4 c) {
    return __builtin_amdgcn_mfma_f32_16x16x32_bf16(a, b, c, 0, 0, 0);
}

// mask dtype sniffing: bit1 => f32 mask, bit0 => u8 mask, none => i32
__device__ __forceinline__ float mask_at(const void* mp, int flag, int i) {
    if (flag & 2) return ((const float*)mp)[i];
    if (flag & 1) return ((const unsigned char*)mp)[i] ? 1.f : 0.f;
    return ((const int*)mp)[i] ? 1.f : 0.f;
}

// prep: detect | pack(Wenc[0:256]) | pack(Wupd) | type_bias | zero-deg | dummy
__global__ __launch_bounds__(256) void k_prep(
    const unsigned int* __restrict__ mw, int nmw, int* __restrict__ flag,
    const float* __restrict__ Wenc, u16* __restrict__ WeP,
    const float* __restrict__ Wupd, u16* __restrict__ WuP,
    const float* __restrict__ ett, const float* __restrict__ benc,
    float* __restrict__ tb, int* __restrict__ deg,
    float4* __restrict__ dummy) {
    __shared__ float s_e[NTy * TEe];
    const int bid = blockIdx.x;
    const int tid = threadIdx.x;

    if (bid < PB_DET) {                        // ---- mask dtype detect
        int found = 0;
        for (int i = bid * 256 + tid; i < nmw; i += PB_DET * 256) {
            unsigned int w = mw[i];
            if (w == 0x3F800000u) found |= 2;
            else if (w > 1u) found |= 1;
        }
        __shared__ int sf;
        if (tid == 0) sf = 0;
        __syncthreads();
        if (found) atomicOr(&sf, found);
        __syncthreads();
        if (tid == 0 && sf) atomicOr(flag, sf);
    } else if (bid < PB_DET + PB_PKE) {        // ---- pack Wenc rows 0..255
        int t = (bid - PB_DET) * 256 + tid;
        int lane = t & 63, tile = t >> 6;
        int kt = tile % KTE, nt = tile / KTE;
        int kbase = kt * 32 + (lane >> 4) * 8;
        int col = nt * 16 + (lane & 15);
        u16 tmp[8];
        #pragma unroll
        for (int j = 0; j < 8; j++)
            tmp[j] = f2bf(Wenc[(size_t)(kbase + j) * Hh + col]);
        *(uint4*)(WeP + (size_t)t * 8) = *(const uint4*)tmp;
    } else if (bid < PB_DET + PB_PKE + PB_PKU) {   // ---- pack Wupd
        int t = (bid - PB_DET - PB_PKE) * 256 + tid;
        int lane = t & 63, tile = t >> 6;
        int kt = tile % KTU, nt = tile / KTU;
        int kbase = kt * 32 + (lane >> 4) * 8;
        int col = nt * 16 + (lane & 15);
        u16 tmp[8];
        #pragma unroll
        for (int j = 0; j < 8; j++)
            tmp[j] = f2bf(Wupd[(size_t)(kbase + j) * Hh + col]);
        *(uint4*)(WuP + (size_t)t * 8) = *(const uint4*)tmp;
    } else if (bid < PB_DET + PB_PKE + PB_PKU + PB_TB) {   // ---- type_bias
        for (int i = tid; i < NTy * TEe; i += 256) s_e[i] = ett[i];
        __syncthreads();
        float b = benc[tid];
        for (int t = 0; t < NTy; t++) {
            float acc = b;
            #pragma unroll 8
            for (int k = 0; k < TEe; k++)
                acc = fmaf(s_e[t * TEe + k], Wenc[(size_t)(Hh + k) * Hh + tid], acc);
            tb[t * Hh + tid] = acc;
        }
    } else if (bid < PB_DET + PB_PKE + PB_PKU + PB_TB + PB_ZD) {  // ---- zero deg
        for (int i = (bid - PB_DET - PB_PKE - PB_PKU - PB_TB) * 256 + tid;
             i < BN; i += PB_ZD * 256)
            deg[i] = 0;
    } else {                                   // ---- zero efW2 dummy row
        if (tid < Hh * 2 / 16) {
            float4 z; z.x = 0.f; z.y = 0.f; z.z = 0.f; z.w = 0.f;
            dummy[tid] = z;
        }
    }
}

// INTERLEAVED fill | wave-specialized dual GEMM (512 threads)
// GEMM role: waves 0-3 compute nfWe1 = nf@We1; waves 4-7 compute nfW1 = nf@W1
__global__ __launch_bounds__(512) void k_fill_dual(
    const int* __restrict__ members, const void* __restrict__ maskp,
    const int* __restrict__ flagp, int* __restrict__ deg,
    int* __restrict__ list2,
    const float* __restrict__ nf, const bf16x8* __restrict__ WeP,
    const bf16x8* __restrict__ WuP, uint4* __restrict__ nfWe1,
    uint4* __restrict__ nfW1) {
    __shared__ __align__(16) u16 s_a[32][LDA];   // 16.9 KB
    const int bid = blockIdx.x;
    const int tid = threadIdx.x;

    if (bid % 3 == 2) {                       // ---- bucket fill (625 blocks)
        const int fbid = bid / 3;
        int flag = flagp[0];
        int i = fbid * 512 + tid;             // exactly BE*Aa threads total
        if (mask_at(maskp, flag, i) != 0.f) {
            int ge = i >> 3;
            int b = ge / Ee;
            int idx = min(max(members[i], 0), Nn - 1);
            int node = b * Nn + idx;
            int slot = atomicAdd(&deg[node], 1);
            if (slot < CAP) list2[(size_t)node * CAP + slot] = ge;
        }
        return;
    }
    // ---- dual GEMM role (wave-specialized)
    const int gbid = (bid / 3) * 2 + (bid % 3);
    if (gbid >= BN / 32) return;
    const int n0 = gbid * 32;
    const int w = tid >> 6, lane = tid & 63;
    const int l15 = lane & 15, lg = lane >> 4;
    const int isU = w >> 2;           // wave-uniform
    const int wc  = w & 3;

    {   // stage nf f32 -> bf16 LDS (all 512 threads)
        const float4* nf4 = (const float4*)nf + (size_t)n0 * 64;
        #pragma unroll
        for (int i = 0; i < 4; i++) {
            int idx = i * 512 + tid;
            int r = idx >> 6, cc = idx & 63;
            float4 v = nf4[r * 64 + cc];
            ushort4 u; u.x = f2bf(v.x); u.y = f2bf(v.y);
            u.z = f2bf(v.z); u.w = f2bf(v.w);
            *(ushort4*)&s_a[r][cc * 4] = u;
        }
    }
    __syncthreads();

    f32x4 acc[2][4];
    #pragma unroll
    for (int m = 0; m < 2; m++)
        #pragma unroll
        for (int n = 0; n < 4; n++) acc[m][n] = (f32x4){0.f, 0.f, 0.f, 0.f};

    const bf16x8* Wp = isU ? WuP : WeP;
    const int kstride = isU ? KTU : KTE;   // W1 = Wupd kt 0..7
    #pragma unroll
    for (int kt = 0; kt < 8; kt++) {
        bf16x8 afr[2], bfr[4];
        #pragma unroll
        for (int n = 0; n < 4; n++)
            bfr[n] = Wp[((size_t)((wc * 4 + n) * kstride + kt)) * 64 + lane];
        #pragma unroll
        for (int m = 0; m < 2; m++)
            afr[m] = *(const bf16x8*)&s_a[m * 16 + l15][kt * 32 + lg * 8];
        #pragma unroll
        for (int m = 0; m < 2; m++)
            #pragma unroll
            for (int n = 0; n < 4; n++)
                acc[m][n] = mfma16(afr[m], bfr[n], acc[m][n]);
    }
    __syncthreads();
    // E waves deposit -> store nfWe1
    if (!isU) {
        #pragma unroll
        for (int m = 0; m < 2; m++)
            #pragma unroll
            for (int j = 0; j < 4; j++) {
                int r = m * 16 + lg * 4 + j;
                #pragma unroll
                for (int n = 0; n < 4; n++)
                    s_a[r][wc * 64 + n * 16 + l15] = f2bf(acc[m][n][j]);
            }
    }
    __syncthreads();
    {
        const uint4* sa4 = (const uint4*)&s_a[0][0];
        #pragma unroll
        for (int i = 0; i < 2; i++) {
            int idx = i * 512 + tid;
            int r = idx >> 5, cc = idx & 31;
            nfWe1[(size_t)(n0 + r) * 32 + cc] = sa4[r * 33 + cc];
        }
    }
    __syncthreads();
    // U waves deposit -> store nfW1
    if (isU) {
        #pragma unroll
        for (int m = 0; m < 2; m++)
            #pragma unroll
            for (int j = 0; j < 4; j++) {
                int r = m * 16 + lg * 4 + j;
                #pragma unroll
                for (int n = 0; n < 4; n++)
                    s_a[r][wc * 64 + n * 16 + l15] = f2bf(acc[m][n][j]);
            }
    }
    __syncthreads();
    {
        const uint4* sa4 = (const uint4*)&s_a[0][0];
        #pragma unroll
        for (int i = 0; i < 2; i++) {
            int idx = i * 512 + tid;
            int r = idx >> 5, cc = idx & 31;
            nfW1[(size_t)(n0 + r) * 32 + cc] = sa4[r * 33 + cc];
        }
    }
}

// fused edge phase + W2 GEMM: 32 edges/block; wave w owns edges w*8..w*8+7.
// Gather: half-wave owns a full 256-col row (16B/lane), cross-half merge.
__global__ __launch_bounds__(256) void k_edge_w2(
    const int* __restrict__ members, const void* __restrict__ maskp,
    const int* __restrict__ flagp, const int* __restrict__ types,
    const u16* __restrict__ nfWe1, const float* __restrict__ tb,
    const float* __restrict__ genc, const float* __restrict__ beenc,
    const bf16x8* __restrict__ WuP, uint4* __restrict__ efW2) {
    __shared__ __align__(16) u16 s_a[32][LDA];   // 16.9 KB
    const int tid = threadIdx.x;
    const int e0  = blockIdx.x * 32;
    const int w = tid >> 6, lane = tid & 63;
    const int l15 = lane & 15, lg = lane >> 4;
    const int flag = flagp[0];
    const int colb = (lane & 31) * 8;
    const int half = lane >> 5;
    const int colw = colb + half * 4;

    {
        const int ew0 = e0 + w * 8;
        int base = ew0 * Aa + lane;
        int mem_all = members[base];
        float mv_all = mask_at(maskp, flag, base);
        int er = ew0 + (lane >> 3);
        int idxv = min(max(mem_all, 0), Nn - 1) + ((er >= Ee) ? Nn : 0);

        float4 gm = *(const float4*)(genc + colw);
        float4 bt = *(const float4*)(beenc + colw);

        for (int i = 0; i < 8; i++) {
            int e = ew0 + i;
            float c = 0.f;
            #pragma unroll
            for (int a = 0; a < Aa; a++) c += __shfl(mv_all, i * 8 + a, 64);
            u16x8 v[4]; float mw_[4];
            #pragma unroll
            for (int q = 0; q < 4; q++) {
                int a = 2 * q + half;
                int gi = __shfl(idxv, i * 8 + a, 64);
                mw_[q] = __shfl(mv_all, i * 8 + a, 64);
                v[q] = *(const u16x8*)(nfWe1 + (size_t)gi * Hh + colb);
            }
            float acc[8];
            #pragma unroll
            for (int k = 0; k < 8; k++) acc[k] = 0.f;
            #pragma unroll
            for (int q = 0; q < 4; q++)
                #pragma unroll
                for (int k = 0; k < 8; k++)
                    acc[k] = fmaf(mw_[q], bf2f(v[q][k]), acc[k]);
            #pragma unroll
            for (int k = 0; k < 8; k++) acc[k] += __shfl_xor(acc[k], 32, 64);
            const float rc = 1.f / fmaxf(c, 1.f);
            float x0 = half ? acc[4] : acc[0];
            float x1 = half ? acc[5] : acc[1];
            float x2 = half ? acc[6] : acc[2];
            float x3 = half ? acc[7] : acc[3];
            int t = types[e];
            float4 tbv = *(const float4*)(tb + t * Hh + colw);
            float g0 = gelu_f(fmaf(x0, rc, tbv.x));
            float g1 = gelu_f(fmaf(x1, rc, tbv.y));
            float g2 = gelu_f(fmaf(x2, rc, tbv.z));
            float g3 = gelu_f(fmaf(x3, rc, tbv.w));
            float s  = g0 + g1 + g2 + g3;
            float s2 = fmaf(g0, g0, fmaf(g1, g1, fmaf(g2, g2, g3 * g3)));
            #pragma unroll
            for (int mk = 1; mk < 64; mk <<= 1) {
                s  += __shfl_xor(s, mk, 64);
                s2 += __shfl_xor(s2, mk, 64);
            }
            float mu = s * (1.f / Hh);
            float rs = rsqrtf(s2 * (1.f / Hh) - mu * mu + 1e-5f);
            ushort4 o;
            o.x = f2bf((g0 - mu) * rs * gm.x + bt.x);
            o.y = f2bf((g1 - mu) * rs * gm.y + bt.y);
            o.z = f2bf((g2 - mu) * rs * gm.z + bt.z);
            o.w = f2bf((g3 - mu) * rs * gm.w + bt.w);
            *(ushort4*)&s_a[w * 8 + i][colw] = o;
        }
    }
    __syncthreads();

    f32x4 acc[2][4];
    #pragma unroll
    for (int m = 0; m < 2; m++)
        #pragma unroll
        for (int n = 0; n < 4; n++) acc[m][n] = (f32x4){0.f, 0.f, 0.f, 0.f};

    #pragma unroll
    for (int kt = 0; kt < 8; kt++) {     // Wupd kt 8..15 = W2
        bf16x8 bfr[4], afr[2];
        #pragma unroll
        for (int n = 0; n < 4; n++)
            bfr[n] = WuP[((size_t)((w * 4 + n) * KTU + 8 + kt)) * 64 + lane];
        #pragma unroll
        for (int m = 0; m < 2; m++)
            afr[m] = *(const bf16x8*)&s_a[m * 16 + l15][kt * 32 + lg * 8];
        #pragma unroll
        for (int m = 0; m < 2; m++)
            #pragma unroll
            for (int n = 0; n < 4; n++)
                acc[m][n] = mfma16(afr[m], bfr[n], acc[m][n]);
    }
    __syncthreads();
    #pragma unroll
    for (int m = 0; m < 2; m++)
        #pragma unroll
        for (int j = 0; j < 4; j++) {
            int r = m * 16 + lg * 4 + j;
            #pragma unroll
            for (int n = 0; n < 4; n++)
                s_a[r][w * 64 + n * 16 + l15] = f2bf(acc[m][n][j]);
        }
    __syncthreads();
    const uint4* sa4 = (const uint4*)&s_a[0][0];
    #pragma unroll
    for (int i = 0; i < 4; i++) {
        int idx = i * 256 + tid;
        int r = idx >> 5, cc = idx & 31;
        efW2[(size_t)(e0 + r) * 32 + cc] = sa4[r * 33 + cc];
    }
}

// node finish: half-wave bucket gather-avg efW2 + nfW1 + bias -> gelu -> LN
__global__ __launch_bounds__(512) void k_node_final(
    const u16* __restrict__ efW2, const u16* __restrict__ nfW1,
    const int* __restrict__ deg, const int* __restrict__ list2,
    const float* __restrict__ bupd, const float* __restrict__ gupd,
    const float* __restrict__ beupd, float* __restrict__ out) {
    const int n = (blockIdx.x * 512 + threadIdx.x) >> 6;
    const int lane = threadIdx.x & 63;
    if (n >= BN) return;
    const int d = min(deg[n], CAP);
    const size_t base = (size_t)n * CAP;
    const int colb = (lane & 31) * 8;
    const int half = lane >> 5;
    const int colw = colb + half * 4;

    int lv = (lane < d) ? list2[base + lane] : BE;

    float acc[8];
    #pragma unroll
    for (int k = 0; k < 8; k++) acc[k] = 0.f;

    for (int j0 = 0; j0 < d; j0 += 8) {
        u16x8 v[4];
        #pragma unroll
        for (int q = 0; q < 4; q++) {
            int jj = j0 + 2 * q + half;
            int ge = __shfl(lv, jj & 63, 64);
            if (jj >= d) ge = BE;
            v[q] = *(const u16x8*)(efW2 + (size_t)ge * Hh + colb);
        }
        #pragma unroll
        for (int q = 0; q < 4; q++)
            #pragma unroll
            for (int k = 0; k < 8; k++)
                acc[k] += bf2f(v[q][k]);
    }
    #pragma unroll
    for (int k = 0; k < 8; k++) acc[k] += __shfl_xor(acc[k], 32, 64);

    const float rc = 1.f / fmaxf((float)d, 1.f);
    float x0 = half ? acc[4] : acc[0];
    float x1 = half ? acc[5] : acc[1];
    float x2 = half ? acc[6] : acc[2];
    float x3 = half ? acc[7] : acc[3];
    ushort4 w1 = *(const ushort4*)(nfW1 + (size_t)n * Hh + colw);
    float4 bb = *(const float4*)(bupd + colw);
    float g0 = gelu_f(fmaf(x0, rc, bf2f(w1.x) + bb.x));
    float g1 = gelu_f(fmaf(x1, rc, bf2f(w1.y) + bb.y));
    float g2 = gelu_f(fmaf(x2, rc, bf2f(w1.z) + bb.z));
    float g3 = gelu_f(fmaf(x3, rc, bf2f(w1.w) + bb.w));

    float s  = g0 + g1 + g2 + g3;
    float s2 = fmaf(g0, g0, fmaf(g1, g1, fmaf(g2, g2, g3 * g3)));
    #pragma unroll
    for (int mk = 1; mk < 64; mk <<= 1) {
        s  += __shfl_xor(s, mk, 64);
        s2 += __shfl_xor(s2, mk, 64);
    }
    float mu = s * (1.f / Hh);
    float rs = rsqrtf(s2 * (1.f / Hh) - mu * mu + 1e-5f);

    float4 gm = *(const float4*)(gupd + colw);
    float4 bt = *(const float4*)(beupd + colw);
    float4 o;
    o.x = (g0 - mu) * rs * gm.x + bt.x;
    o.y = (g1 - mu) * rs * gm.y + bt.y;
    o.z = (g2 - mu) * rs * gm.z + bt.z;
    o.w = (g3 - mu) * rs * gm.w + bt.w;
    *(float4*)(out + (size_t)n * Hh + colw) = o;
}

extern "C" void kernel_launch(void* const* d_in, const int* in_sizes, int n_in,
                              void* d_out, int out_size, void* d_ws, size_t ws_size,
                              hipStream_t stream) {
    const float* nf    = (const float*)d_in[0];
    const int* members = (const int*)d_in[1];
    const int* types   = (const int*)d_in[2];
    const void* maskp  = d_in[3];
    const float* ett   = (const float*)d_in[4];
    const float* Wenc  = (const float*)d_in[5];
    const float* benc  = (const float*)d_in[6];
    const float* genc  = (const float*)d_in[7];
    const float* beenc = (const float*)d_in[8];
    const float* Wupd  = (const float*)d_in[9];
    const float* bupd  = (const float*)d_in[10];
    const float* gupd  = (const float*)d_in[11];
    const float* beupd = (const float*)d_in[12];
    float* out = (float*)d_out;

    // workspace layout (~72 MB; ws is 256 MiB)
    int* ip    = (int*)d_ws;
    int* flag  = ip;                      // 64 ints
    int* deg   = ip + 64;                 // BN
    int* list2 = deg + BN;                // BN*CAP (10.24 MB)
    char* p    = (char*)(list2 + (size_t)BN * CAP);
    u16* efW2b  = (u16*)p;   p += (size_t)(BE + 1) * Hh * 2;       // 20.5 MB (+zero row)
    u16* nfW1b  = (u16*)p;   p += (size_t)BN * Hh * 2;             // 20.5 MB
    u16* nfWe1b = (u16*)p;   p += (size_t)BN * Hh * 2;             // 20.5 MB
    u16* We1P   = (u16*)p;   p += (size_t)16 * KTE * 64 * 8 * 2;   // 131 KB
    u16* WupdP  = (u16*)p;   p += (size_t)16 * KTU * 64 * 8 * 2;   // 262 KB
    float* tb   = (float*)p;                                       // 16 KB

    hipMemsetAsync(flag, 0, 256, stream);
    hipLaunchKernelGGL(k_prep, dim3(NPREP), dim3(256), 0, stream,
                       (const unsigned int*)maskp, BE * Aa / 4, flag,
                       Wenc, We1P, Wupd, WupdP, ett, benc, tb, deg,
                       (float4*)(efW2b + (size_t)BE * Hh));
    hipLaunchKernelGGL(k_fill_dual, dim3(NFD), dim3(512), 0, stream,
                       members, maskp, flag, deg, list2,
                       nf, (const bf16x8*)We1P, (const bf16x8*)WupdP,
                       (uint4*)nfWe1b, (uint4*)nfW1b);
    hipLaunchKernelGGL(k_edge_w2, dim3(BE / 32), dim3(256), 0, stream,
                       members, maskp, flag, types, nfWe1b, tb, genc, beenc,
                       (const bf16x8*)WupdP, (uint4*)efW2b);
    hipLaunchKernelGGL(k_node_final, dim3(BN * 64 / 512), dim3(512), 0, stream,
                       efW2b, nfW1b, deg, list2, bupd, gupd, beupd, out);
}